// Round 3
// baseline (609.863 us; speedup 1.0000x reference)
//
#include <hip/hip_runtime.h>
#include <stdint.h>
#include <stddef.h>

// GAT layer, N=12288, IN=512, OUT=256.
//   h = inp@W; s1=h@a1; s2=h@a2; e=lrelu(s1_i+s2_j); mask by adj; row softmax; out=elu(att@h)
// Softmax bound M_i = lrelu(s1_i + max_j s2_j) >= all row scores (lrelu monotone) => single
// pass computes denominator and weighted sum together, no online rescale.
// Round-3 key change: adj (604 MB int32, 1 useful bit each) is read ONCE, fully coalesced,
// and compressed to an 18.9 MB bitmask; K4 consumes the bitmask (L2/L3-resident).
#define NN     12288
#define INF    512
#define OUTF   256
#define ALPHA  0.2f
#define LOG2E  1.44269504088896340736f
#define NWORDS (NN / 64)      // 192 u64 words per row
#define PARTS  8
#define KRANGE (NN / PARTS)   // 1536
#define NIT    (KRANGE / 64)  // 24

typedef __attribute__((ext_vector_type(4))) float          f32x4;
typedef __attribute__((ext_vector_type(8))) short          bf16x8;
typedef __attribute__((ext_vector_type(4))) unsigned int   u32x4;
typedef __attribute__((ext_vector_type(4))) unsigned short u16x4;
typedef unsigned long long u64;

static __device__ __forceinline__ unsigned short f2bf(float f) {
  union { float f; unsigned u; } v; v.f = f;
  unsigned r = v.u + 0x7fffu + ((v.u >> 16) & 1u);   // RNE
  return (unsigned short)(r >> 16);
}
static __device__ __forceinline__ float bf2f(unsigned short s) {
  union { unsigned u; float f; } v; v.u = ((unsigned)s) << 16;
  return v.f;
}

// hT layout (pre-swizzled transposed h, bf16):
//   byte(col,k) = col*(NN*2) + (k>>6)*128 + (((k&63)*2) ^ ((col&7)<<4))
// so a linear 128B chunk copy into LDS yields the XOR-swizzled tile directly.

// ---------------- KA: fused {K1: h GEMM + s1/s2} and {bitmap builder} ----------------------
// blocks [0,384): K1 role. blocks [384, 384+4096): bitmap role (wave-ballot, coalesced).
#define K1_BLOCKS 384
#define BM_BLOCKS 4096

__global__ __launch_bounds__(256) void ka_fused(const float* __restrict__ inp,
                                                const int* __restrict__ adj,
                                                const float* __restrict__ W,
                                                const float* __restrict__ a1,
                                                const float* __restrict__ a2,
                                                unsigned short* __restrict__ hT,
                                                float* __restrict__ s1,
                                                float* __restrict__ s2,
                                                u64* __restrict__ bm) {
  __shared__ __align__(16) float inp_s[32][36];
  __shared__ __align__(16) float W_s[32][256];
  const int t = threadIdx.x;

  if (blockIdx.x >= K1_BLOCKS) {
    // ---- bitmap role: wave handles 144 consecutive u64 words; 1 dword/lane, ballot, store.
    const int wavegid = (blockIdx.x - K1_BLOCKS) * 4 + (t >> 6);
    const int l = t & 63;
    const int w0 = wavegid * 144;
#pragma unroll 4
    for (int i = 0; i < 144; ++i) {
      const int w = w0 + i;
      const int v = adj[(size_t)w * 64 + l];
      const u64 mask = __ballot(v != 0);
      if (l == 0) bm[w] = mask;
    }
    return;
  }

  // ---- K1 role: 32 rows of h, f32 accum; emit hT (bf16 transposed+swizzled) + s1/s2.
  const int row0 = blockIdx.x * 32;
  const int tx = t & 63, ty = t >> 6;
  f32x4 acc[8];
#pragma unroll
  for (int r = 0; r < 8; ++r) acc[r] = f32x4{0.f, 0.f, 0.f, 0.f};
  for (int kc = 0; kc < 16; ++kc) {
    {
      const int r = t >> 3, ko = (t & 7) * 4;
      *(f32x4*)&inp_s[r][ko] = *(const f32x4*)(inp + (size_t)(row0 + r) * INF + kc * 32 + ko);
    }
#pragma unroll
    for (int j = 0; j < 8; ++j) {
      const int r = j * 4 + ty;
      *(f32x4*)&W_s[r][tx * 4] = *(const f32x4*)(W + (size_t)(kc * 32 + r) * OUTF + tx * 4);
    }
    __syncthreads();
#pragma unroll 4
    for (int k = 0; k < 32; ++k) {
      const f32x4 wv = *(const f32x4*)&W_s[k][tx * 4];
#pragma unroll
      for (int rr = 0; rr < 8; ++rr) acc[rr] += inp_s[ty * 8 + rr][k] * wv;
    }
    __syncthreads();
  }
#pragma unroll
  for (int rr = 0; rr < 8; ++rr) *(f32x4*)&W_s[ty * 8 + rr][tx * 4] = acc[rr];
  __syncthreads();
  {
    const int col = t;  // one hT column (= one h feature) per thread
    char* dst = (char*)hT + (size_t)col * (NN * 2) + (size_t)(row0 >> 6) * 128;
    const unsigned swz = (unsigned)((col & 7) << 4);
    const unsigned wbase = (unsigned)(row0 & 63) * 2;
#pragma unroll
    for (int s = 0; s < 4; ++s) {
      unsigned e0 = (unsigned)f2bf(W_s[s*8+0][col]) | ((unsigned)f2bf(W_s[s*8+1][col]) << 16);
      unsigned e1 = (unsigned)f2bf(W_s[s*8+2][col]) | ((unsigned)f2bf(W_s[s*8+3][col]) << 16);
      unsigned e2 = (unsigned)f2bf(W_s[s*8+4][col]) | ((unsigned)f2bf(W_s[s*8+5][col]) << 16);
      unsigned e3 = (unsigned)f2bf(W_s[s*8+6][col]) | ((unsigned)f2bf(W_s[s*8+7][col]) << 16);
      u32x4 p; p.x = e0; p.y = e1; p.z = e2; p.w = e3;
      *(u32x4*)(dst + ((wbase + (unsigned)s * 16) ^ swz)) = p;
    }
  }
  // ---- fused s1/s2: h tile is in W_s (f32). 8 threads per row, shuffle-reduce.
  {
    const int r = t >> 3, seg = t & 7;
    const float* hrow = &W_s[r][seg * 32];
    float v1 = 0.f, v2 = 0.f;
#pragma unroll
    for (int dd = 0; dd < 32; dd += 4) {
      const f32x4 hv  = *(const f32x4*)(hrow + dd);
      const f32x4 a1v = *(const f32x4*)(a1 + seg * 32 + dd);
      const f32x4 a2v = *(const f32x4*)(a2 + seg * 32 + dd);
      v1 += hv.x*a1v.x + hv.y*a1v.y + hv.z*a1v.z + hv.w*a1v.w;
      v2 += hv.x*a2v.x + hv.y*a2v.y + hv.z*a2v.z + hv.w*a2v.w;
    }
    v1 += __shfl_xor(v1, 1); v1 += __shfl_xor(v1, 2); v1 += __shfl_xor(v1, 4);
    v2 += __shfl_xor(v2, 1); v2 += __shfl_xor(v2, 2); v2 += __shfl_xor(v2, 4);
    if (seg == 0) { s1[row0 + r] = v1; s2[row0 + r] = v2; }
  }
}

// ---------------- K3: S2MAX = max(s2) -----------------------------------------------------
__global__ __launch_bounds__(1024) void k3_s2max(const float* __restrict__ s2,
                                                 float* __restrict__ s2max) {
  __shared__ float red[1024];
  const int t = threadIdx.x;
  float m = -3.0e38f;
  for (int j = t; j < NN; j += 1024) m = fmaxf(m, s2[j]);
  red[t] = m;
  __syncthreads();
  for (int s = 512; s > 0; s >>= 1) {
    if (t < s) red[t] = fmaxf(red[t], red[t + s]);
    __syncthreads();
  }
  if (t == 0) s2max[0] = red[0];
}

// ---------------- K4 v3: flash-style masked softmax-PV, bitmask-driven ---------------------
// 96 row-blocks (128 rows) x 8 k-parts = 768 blocks; XCD-swizzled so each XCD owns one part
// (B slice 786 KB + bitmap slice 2.4 MB both L2-resident). 4 waves; wave = 32 rows x 256 cols.
// Attention weights computed directly into MFMA A-fragments; B_lds dbuf; one raw barrier/iter
// with counted vmcnt(2) so the 2 bitmap prefetch loads stay in flight across it.

#define GLDS16(SRC, DST)                                                        \
  __builtin_amdgcn_global_load_lds(                                             \
      (const __attribute__((address_space(1))) unsigned int*)(SRC),             \
      (__attribute__((address_space(3))) unsigned int*)(DST), 16, 0, 0)

#define K4_STAGE(BUF, IT)                                                       \
  do {                                                                          \
    const size_t _coff = (size_t)(kword0 + (IT)) * 128;                         \
    _Pragma("unroll") for (int _p = 0; _p < 8; ++_p) {                          \
      const int _idx = _p * 256 + t;                                            \
      const char* _src = (const char*)hT + (size_t)(_idx >> 3) * (NN * 2) +     \
                         _coff + (size_t)(_idx & 7) * 16;                       \
      GLDS16(_src, (char*)B_lds + (size_t)(BUF) * 32768 +                       \
                       (size_t)(_p * 256 + (wv << 6)) * 16);                    \
    }                                                                           \
  } while (0)

#define K4_PREFETCH(DST, IT)                                                    \
  do {                                                                          \
    DST[0] = bmrow0[kword0 + (IT)];                                             \
    DST[1] = bmrow1[kword0 + (IT)];                                             \
  } while (0)

#define K4_COMPUTE(BMC, IT)                                                     \
  do {                                                                          \
    _Pragma("unroll") for (int _kt = 0; _kt < 2; ++_kt) {                       \
      const f32x4 _sa = *(const f32x4*)(s2_lds + (IT) * 64 + _kt * 32 + ko * 8);\
      const f32x4 _sb = *(const f32x4*)(s2_lds + (IT) * 64 + _kt * 32 + ko * 8 + 4);\
      _Pragma("unroll") for (int _rt = 0; _rt < 2; ++_rt) {                     \
        const unsigned _byte =                                                  \
            (unsigned)(BMC[_rt] >> (_kt * 32 + ko * 8)) & 0xFFu;                \
        bf16x8 _f;                                                              \
        _Pragma("unroll") for (int _j = 0; _j < 4; ++_j) {                      \
          const float _tt = s1v[_rt] + _sa[_j];                                 \
          const float _e = fmaxf(_tt, ALPHA * _tt);                             \
          float _w = 0.f;                                                       \
          if (_byte & (1u << _j))                                               \
            _w = exp2f(__builtin_fmaf(_e, LOG2E, -ML2[_rt]));                   \
          dsum[_rt] += _w;                                                      \
          _f[_j] = (short)f2bf(_w);                                             \
        }                                                                       \
        _Pragma("unroll") for (int _j = 0; _j < 4; ++_j) {                      \
          const float _tt = s1v[_rt] + _sb[_j];                                 \
          const float _e = fmaxf(_tt, ALPHA * _tt);                             \
          float _w = 0.f;                                                       \
          if (_byte & (16u << _j))                                              \
            _w = exp2f(__builtin_fmaf(_e, LOG2E, -ML2[_rt]));                   \
          dsum[_rt] += _w;                                                      \
          _f[4 + _j] = (short)f2bf(_w);                                         \
        }                                                                       \
        frag[_rt][_kt] = _f;                                                    \
      }                                                                         \
    }                                                                           \
  } while (0)

#define K4_MFMA(BUF)                                                            \
  do {                                                                          \
    const char* _Bb = (const char*)B_lds + (size_t)(BUF) * 32768;               \
    _Pragma("unroll") for (int _kt = 0; _kt < 2; ++_kt) {                       \
      const unsigned _kb = (unsigned)((_kt * 32 + ko * 8) * 2);                 \
      _Pragma("unroll") for (int _ct = 0; _ct < 16; ++_ct) {                    \
        const int _col = _ct * 16 + m;                                          \
        const bf16x8 _b = *(const bf16x8*)(_Bb + _col * 128 +                   \
                              (_kb ^ ((unsigned)((_col & 7) << 4))));           \
        acc[0][_ct] = __builtin_amdgcn_mfma_f32_16x16x32_bf16(frag[0][_kt], _b, \
                                                              acc[0][_ct], 0, 0, 0);\
        acc[1][_ct] = __builtin_amdgcn_mfma_f32_16x16x32_bf16(frag[1][_kt], _b, \
                                                              acc[1][_ct], 0, 0, 0);\
      }                                                                         \
    }                                                                           \
  } while (0)

#define K4_BARRIER()                                                            \
  do {                                                                          \
    asm volatile("s_waitcnt vmcnt(2)" ::: "memory");                            \
    __builtin_amdgcn_sched_barrier(0);                                          \
    __builtin_amdgcn_s_barrier();                                               \
    __builtin_amdgcn_sched_barrier(0);                                          \
  } while (0)

#define K4_SUB(IT, BUF, BCUR, BNXT, ISLAST)                                     \
  do {                                                                          \
    if (!(ISLAST)) {                                                            \
      K4_STAGE((BUF) ^ 1, (IT) + 1);                                            \
      __builtin_amdgcn_sched_barrier(0);                                        \
    }                                                                           \
    K4_COMPUTE(BCUR, IT);                                                       \
    if (!(ISLAST)) K4_PREFETCH(BNXT, (IT) + 1);                                 \
    K4_MFMA(BUF);                                                               \
    if (!(ISLAST)) K4_BARRIER();                                                \
  } while (0)

__global__ __launch_bounds__(256, 2) void k4_attn(const u64* __restrict__ bm,
                                                  const unsigned short* __restrict__ hT,
                                                  const float* __restrict__ s1,
                                                  const float* __restrict__ s2,
                                                  const float* __restrict__ s2max,
                                                  unsigned short* __restrict__ accp,
                                                  float* __restrict__ denp) {
  __shared__ __align__(16) char B_lds[2][256 * 128];
  __shared__ __align__(16) float s2_lds[KRANGE];
  const int t = threadIdx.x;
  const int wv = t >> 6, l = t & 63;
  const int m = l & 15, ko = l >> 4;
  // bijective XCD swizzle: round-robin bid%8 = XCD -> each XCD owns exactly one k-part.
  const int wgid = (blockIdx.x % 8) * 96 + blockIdx.x / 8;
  const int part = wgid / 96, rb = wgid % 96;
  const int row0 = rb * 128 + wv * 32;  // this wave's first row
  const int kbase = part * KRANGE;
  const int kword0 = kbase >> 6;

  const float S2MAX = s2max[0];
  float s1v[2], ML2[2], dsum[2];
#pragma unroll
  for (int rt = 0; rt < 2; ++rt) {
    s1v[rt] = s1[row0 + rt * 16 + m];
    const float tup = s1v[rt] + S2MAX;
    const float M = fmaxf(tup, ALPHA * tup);  // lrelu upper bound for this row
    ML2[rt] = M * LOG2E;
    dsum[rt] = 0.f;
  }
  f32x4 acc[2][16];
#pragma unroll
  for (int rt = 0; rt < 2; ++rt)
#pragma unroll
    for (int ct = 0; ct < 16; ++ct) acc[rt][ct] = f32x4{0.f, 0.f, 0.f, 0.f};

  const u64* bmrow0 = bm + (size_t)(row0 + m) * NWORDS;
  const u64* bmrow1 = bm + (size_t)(row0 + 16 + m) * NWORDS;
  u64 bmE[2], bmO[2];
  bf16x8 frag[2][2];

  // prologue: s2 tile -> LDS (6 KB), B tile 0 -> LDS, bitmap word 0 -> regs
  {
    GLDS16((const char*)(s2 + kbase) + (size_t)t * 16,
           (char*)s2_lds + (size_t)(wv << 6) * 16);
    if (t < 128)
      GLDS16((const char*)(s2 + kbase) + (size_t)(256 + t) * 16,
             (char*)s2_lds + (size_t)(256 + (wv << 6)) * 16);
    K4_STAGE(0, 0);
    __builtin_amdgcn_sched_barrier(0);
    K4_PREFETCH(bmE, 0);
    K4_BARRIER();  // vmcnt(2): waits s2+B0, leaves the 2 bitmap loads in flight
  }

#pragma unroll 1
  for (int it = 0; it < NIT - 2; it += 2) {
    K4_SUB(it, 0, bmE, bmO, false);
    K4_SUB(it + 1, 1, bmO, bmE, false);
  }
  K4_SUB(NIT - 2, 0, bmE, bmO, false);
  K4_SUB(NIT - 1, 1, bmO, bmE, true);

  // denominator: sum the 4 k-octet lanes of each row
#pragma unroll
  for (int rt = 0; rt < 2; ++rt) {
    dsum[rt] += __shfl_xor(dsum[rt], 16);
    dsum[rt] += __shfl_xor(dsum[rt], 32);
  }
  if (l < 16) {
    denp[(size_t)part * NN + row0 + l] = dsum[0];
    denp[(size_t)part * NN + row0 + 16 + l] = dsum[1];
  }
  unsigned short* ap = accp + (size_t)part * NN * OUTF;
#pragma unroll
  for (int rt = 0; rt < 2; ++rt)
#pragma unroll
    for (int ct = 0; ct < 16; ++ct) {
      const int col = ct * 16 + m;
      const int grow = row0 + rt * 16 + ko * 4;
#pragma unroll
      for (int j = 0; j < 4; ++j)
        ap[(size_t)(grow + j) * OUTF + col] = f2bf(acc[rt][ct][j]);
    }
}

// ---------------- K5: combine 8 bf16 partials, divide, ELU ---------------------------------
__global__ __launch_bounds__(256) void k5_combine(const unsigned short* __restrict__ accp,
                                                  const float* __restrict__ denp,
                                                  float* __restrict__ out) {
  const int idx = blockIdx.x * 256 + threadIdx.x;  // 4 floats per thread
  const int row = idx >> 6;
  f32x4 v = f32x4{0.f, 0.f, 0.f, 0.f};
  float den = 0.f;
#pragma unroll
  for (int p = 0; p < PARTS; ++p) {
    const u16x4 pv = *(const u16x4*)(accp + (size_t)p * NN * OUTF + (size_t)idx * 4);
    v.x += bf2f(pv.x); v.y += bf2f(pv.y); v.z += bf2f(pv.z); v.w += bf2f(pv.w);
    den += denp[(size_t)p * NN + row];
  }
  const float inv = 1.f / den;
  f32x4 r;
#pragma unroll
  for (int j = 0; j < 4; ++j) {
    const float x = v[j] * inv;
    r[j] = x > 0.f ? x : (__expf(x) - 1.f);
  }
  *(f32x4*)(out + (size_t)idx * 4) = r;
}

// ---------------- launch -------------------------------------------------------------------
extern "C" void kernel_launch(void* const* d_in, const int* in_sizes, int n_in,
                              void* d_out, int out_size, void* d_ws, size_t ws_size,
                              hipStream_t stream) {
  const float* inp = (const float*)d_in[0];
  const int*   adj = (const int*)d_in[1];
  const float* W   = (const float*)d_in[2];
  const float* a1  = (const float*)d_in[3];
  const float* a2  = (const float*)d_in[4];
  float* out = (float*)d_out;
  char* ws = (char*)d_ws;

  // ws layout (~76 MB; harness provides ~2.4 GB per fill counters)
  unsigned short* hT  = (unsigned short*)(ws + 0);            //  6,291,456 B
  float* s1   = (float*)(ws + 6291456);                       //     49,152 B
  float* s2   = (float*)(ws + 6340608);                       //     49,152 B
  float* s2m  = (float*)(ws + 6389760);                       //        256 B
  u64*   bmp  = (u64*)(ws + 6390016);                         // 18,874,368 B
  unsigned short* accp = (unsigned short*)(ws + 25264384);    // 50,331,648 B (bf16 x 8 parts)
  float* denp = (float*)(ws + 75596032);                      //    393,216 B

  ka_fused<<<dim3(K1_BLOCKS + BM_BLOCKS), dim3(256), 0, stream>>>(inp, adj, W, a1, a2,
                                                                  hT, s1, s2, bmp);
  k3_s2max<<<dim3(1), dim3(1024), 0, stream>>>(s2, s2m);
  k4_attn<<<dim3(96 * PARTS), dim3(256), 0, stream>>>(bmp, hT, s1, s2, s2m, accp, denp);
  k5_combine<<<dim3(NN * OUTF / 1024), dim3(256), 0, stream>>>(accp, denp, out);
}

// Round 4
// 421.196 us; speedup vs baseline: 1.4479x; 1.4479x over previous
//
#include <hip/hip_runtime.h>
#include <stdint.h>
#include <stddef.h>

// GAT layer, N=12288, IN=512, OUT=256.
//   h = inp@W; s1=h@a1; s2=h@a2; e=lrelu(s1_i+s2_j); mask by adj; row softmax; out=elu(att@h)
// Softmax bound M_i = lrelu(s1_i + max_j s2_j) >= all row scores (lrelu monotone) => single
// pass computes denominator and weighted sum together, no online rescale.
// Round-4: adj (604 MB) is compressed by a dedicated copy-kernel-shaped pass (dwordx4/lane
// fully coalesced, no ballot, no LDS) into an 18.9 MB byte bitmap; K4 consumes the bitmap.
#define NN     12288
#define INF    512
#define OUTF   256
#define ALPHA  0.2f
#define LOG2E  1.44269504088896340736f
#define PARTS  16
#define KRANGE (NN / PARTS)   // 768
#define NIT    (KRANGE / 64)  // 12

typedef __attribute__((ext_vector_type(4))) float          f32x4;
typedef __attribute__((ext_vector_type(8))) short          bf16x8;
typedef __attribute__((ext_vector_type(4))) unsigned int   u32x4;
typedef __attribute__((ext_vector_type(2))) unsigned int   u32x2;
typedef __attribute__((ext_vector_type(4))) unsigned short u16x4;

static __device__ __forceinline__ unsigned short f2bf(float f) {
  union { float f; unsigned u; } v; v.f = f;
  unsigned r = v.u + 0x7fffu + ((v.u >> 16) & 1u);   // RNE
  return (unsigned short)(r >> 16);
}
static __device__ __forceinline__ float bf2f(unsigned short s) {
  union { unsigned u; float f; } v; v.u = ((unsigned)s) << 16;
  return v.f;
}

// hT layout (pre-swizzled transposed h, bf16):
//   byte(col,k) = col*(NN*2) + (k>>6)*128 + (((k&63)*2) ^ ((col&7)<<4))

// ---------------- KC: adj -> byte bitmap, copy-kernel-shaped -------------------------------
// 2048 blocks x 256. Lane l loads dwordx4 at +l*16 (perfect coalescing, 1KB/wave/instr).
// 4 ints -> nibble in-lane; one shfl_xor(1) pairs nibbles into a byte; even lanes store.
// bm byte b covers flat cols [8b, 8b+8) i.e. bm[row*1536 + oct], bit j = col oct*8+j.
__global__ __launch_bounds__(256) void kc_bitmap(const int* __restrict__ adj,
                                                 unsigned char* __restrict__ bm) {
  const int t = threadIdx.x, l = t & 63, wv = t >> 6;
  const int gw = blockIdx.x * 4 + wv;            // 0..8191
  const int* ip = adj + (size_t)gw * 18432 + l * 4;
  unsigned char* ob = bm + (size_t)gw * 2304 + (l >> 1);
  const bool writer = (l & 1) == 0;
  for (int i = 0; i < 72; i += 4) {
    u32x4 x[4];
#pragma unroll
    for (int u = 0; u < 4; ++u)
      x[u] = *(const u32x4*)(ip + (size_t)(i + u) * 256);
#pragma unroll
    for (int u = 0; u < 4; ++u) {
      const unsigned nib = min(x[u].x, 1u) | (min(x[u].y, 1u) << 1) |
                           (min(x[u].z, 1u) << 2) | (min(x[u].w, 1u) << 3);
      const unsigned other = (unsigned)__shfl_xor((int)nib, 1);
      if (writer) ob[(i + u) * 32] = (unsigned char)(nib | (other << 4));
    }
  }
}

// ---------------- K1: h = inp@W (f32 accum) -> hT (bf16 swizzled) + fused s1/s2 -----------
__global__ __launch_bounds__(256) void k1_gemm_h(const float* __restrict__ inp,
                                                 const float* __restrict__ W,
                                                 const float* __restrict__ a1,
                                                 const float* __restrict__ a2,
                                                 unsigned short* __restrict__ hT,
                                                 float* __restrict__ s1,
                                                 float* __restrict__ s2) {
  __shared__ __align__(16) float inp_s[32][36];
  __shared__ __align__(16) float W_s[32][256];
  const int t = threadIdx.x;
  const int row0 = blockIdx.x * 32;
  const int tx = t & 63, ty = t >> 6;
  f32x4 acc[8];
#pragma unroll
  for (int r = 0; r < 8; ++r) acc[r] = f32x4{0.f, 0.f, 0.f, 0.f};
  for (int kc = 0; kc < 16; ++kc) {
    {
      const int r = t >> 3, ko = (t & 7) * 4;
      *(f32x4*)&inp_s[r][ko] = *(const f32x4*)(inp + (size_t)(row0 + r) * INF + kc * 32 + ko);
    }
#pragma unroll
    for (int j = 0; j < 8; ++j) {
      const int r = j * 4 + ty;
      *(f32x4*)&W_s[r][tx * 4] = *(const f32x4*)(W + (size_t)(kc * 32 + r) * OUTF + tx * 4);
    }
    __syncthreads();
#pragma unroll 4
    for (int k = 0; k < 32; ++k) {
      const f32x4 wv = *(const f32x4*)&W_s[k][tx * 4];
#pragma unroll
      for (int rr = 0; rr < 8; ++rr) acc[rr] += inp_s[ty * 8 + rr][k] * wv;
    }
    __syncthreads();
  }
#pragma unroll
  for (int rr = 0; rr < 8; ++rr) *(f32x4*)&W_s[ty * 8 + rr][tx * 4] = acc[rr];
  __syncthreads();
  {
    const int col = t;  // one hT column (= one h feature) per thread
    char* dst = (char*)hT + (size_t)col * (NN * 2) + (size_t)(row0 >> 6) * 128;
    const unsigned swz = (unsigned)((col & 7) << 4);
    const unsigned wbase = (unsigned)(row0 & 63) * 2;
#pragma unroll
    for (int s = 0; s < 4; ++s) {
      unsigned e0 = (unsigned)f2bf(W_s[s*8+0][col]) | ((unsigned)f2bf(W_s[s*8+1][col]) << 16);
      unsigned e1 = (unsigned)f2bf(W_s[s*8+2][col]) | ((unsigned)f2bf(W_s[s*8+3][col]) << 16);
      unsigned e2 = (unsigned)f2bf(W_s[s*8+4][col]) | ((unsigned)f2bf(W_s[s*8+5][col]) << 16);
      unsigned e3 = (unsigned)f2bf(W_s[s*8+6][col]) | ((unsigned)f2bf(W_s[s*8+7][col]) << 16);
      u32x4 p; p.x = e0; p.y = e1; p.z = e2; p.w = e3;
      *(u32x4*)(dst + ((wbase + (unsigned)s * 16) ^ swz)) = p;
    }
  }
  // fused s1/s2: h tile is in W_s (f32). 8 threads per row, shuffle-reduce.
  {
    const int r = t >> 3, seg = t & 7;
    const float* hrow = &W_s[r][seg * 32];
    float v1 = 0.f, v2 = 0.f;
#pragma unroll
    for (int dd = 0; dd < 32; dd += 4) {
      const f32x4 hv  = *(const f32x4*)(hrow + dd);
      const f32x4 a1v = *(const f32x4*)(a1 + seg * 32 + dd);
      const f32x4 a2v = *(const f32x4*)(a2 + seg * 32 + dd);
      v1 += hv.x*a1v.x + hv.y*a1v.y + hv.z*a1v.z + hv.w*a1v.w;
      v2 += hv.x*a2v.x + hv.y*a2v.y + hv.z*a2v.z + hv.w*a2v.w;
    }
    v1 += __shfl_xor(v1, 1); v1 += __shfl_xor(v1, 2); v1 += __shfl_xor(v1, 4);
    v2 += __shfl_xor(v2, 1); v2 += __shfl_xor(v2, 2); v2 += __shfl_xor(v2, 4);
    if (seg == 0) { s1[row0 + r] = v1; s2[row0 + r] = v2; }
  }
}

// ---------------- K3: S2MAX = max(s2) -----------------------------------------------------
__global__ __launch_bounds__(1024) void k3_s2max(const float* __restrict__ s2,
                                                 float* __restrict__ s2max) {
  __shared__ float red[1024];
  const int t = threadIdx.x;
  float m = -3.0e38f;
  for (int j = t; j < NN; j += 1024) m = fmaxf(m, s2[j]);
  red[t] = m;
  __syncthreads();
  for (int s = 512; s > 0; s >>= 1) {
    if (t < s) red[t] = fmaxf(red[t], red[t + s]);
    __syncthreads();
  }
  if (t == 0) s2max[0] = red[0];
}

// ---------------- K4 v4: flash-style masked softmax-PV, byte-bitmap-driven -----------------
// 96 row-blocks (128 rows) x 16 k-parts = 1536 blocks (exactly 3 even residency rounds).
// XCD swizzle pins 2 parts per XCD (bm slice + B slice L2-resident). 4 waves; wave = 32 rows
// x 256 cols. Attention weights computed directly into MFMA A-fragments; B_lds dbuf; one raw
// barrier/iter with counted vmcnt(2) so the 2 bitmap prefetch loads stay in flight across it.

#define GLDS16(SRC, DST)                                                        \
  __builtin_amdgcn_global_load_lds(                                             \
      (const __attribute__((address_space(1))) unsigned int*)(SRC),             \
      (__attribute__((address_space(3))) unsigned int*)(DST), 16, 0, 0)

#define K4_STAGE(BUF, IT)                                                       \
  do {                                                                          \
    const size_t _coff = (size_t)(kword0 + (IT)) * 128;                         \
    _Pragma("unroll") for (int _p = 0; _p < 8; ++_p) {                          \
      const int _idx = _p * 256 + t;                                            \
      const char* _src = (const char*)hT + (size_t)(_idx >> 3) * (NN * 2) +     \
                         _coff + (size_t)(_idx & 7) * 16;                       \
      GLDS16(_src, (char*)B_lds + (size_t)(BUF) * 32768 +                       \
                       (size_t)(_p * 256 + (wv << 6)) * 16);                    \
    }                                                                           \
  } while (0)

#define K4_PREFETCH(DST, IT)                                                    \
  do {                                                                          \
    DST[0] = *(const u32x2*)(bmr0 + (IT) * 8);                                  \
    DST[1] = *(const u32x2*)(bmr1 + (IT) * 8);                                  \
  } while (0)

#define K4_COMPUTE(BMC, IT)                                                     \
  do {                                                                          \
    _Pragma("unroll") for (int _kt = 0; _kt < 2; ++_kt) {                       \
      const f32x4 _sa = *(const f32x4*)(s2_lds + (IT) * 64 + _kt * 32 + ko * 8);\
      const f32x4 _sb = *(const f32x4*)(s2_lds + (IT) * 64 + _kt * 32 + ko * 8 + 4);\
      _Pragma("unroll") for (int _rt = 0; _rt < 2; ++_rt) {                     \
        const unsigned _w32 = (_kt == 0) ? BMC[_rt].x : BMC[_rt].y;             \
        const unsigned _byte = (_w32 >> ko8) & 0xFFu;                           \
        bf16x8 _f;                                                              \
        _Pragma("unroll") for (int _j = 0; _j < 4; ++_j) {                      \
          const float _tt = s1v[_rt] + _sa[_j];                                 \
          const float _e = fmaxf(_tt, ALPHA * _tt);                             \
          float _w = 0.f;                                                       \
          if (_byte & (1u << _j))                                               \
            _w = exp2f(__builtin_fmaf(_e, LOG2E, -ML2[_rt]));                   \
          dsum[_rt] += _w;                                                      \
          _f[_j] = (short)f2bf(_w);                                            \
        }                                                                       \
        _Pragma("unroll") for (int _j = 0; _j < 4; ++_j) {                      \
          const float _tt = s1v[_rt] + _sb[_j];                                 \
          const float _e = fmaxf(_tt, ALPHA * _tt);                             \
          float _w = 0.f;                                                       \
          if (_byte & (16u << _j))                                              \
            _w = exp2f(__builtin_fmaf(_e, LOG2E, -ML2[_rt]));                   \
          dsum[_rt] += _w;                                                      \
          _f[4 + _j] = (short)f2bf(_w);                                        \
        }                                                                       \
        frag[_rt][_kt] = _f;                                                    \
      }                                                                         \
    }                                                                           \
  } while (0)

#define K4_MFMA(BUF)                                                            \
  do {                                                                          \
    const char* _Bb = (const char*)B_lds + (size_t)(BUF) * 32768;               \
    _Pragma("unroll") for (int _kt = 0; _kt < 2; ++_kt) {                       \
      const unsigned _kb = (unsigned)((_kt * 32 + ko * 8) * 2);                 \
      _Pragma("unroll") for (int _ct = 0; _ct < 16; ++_ct) {                    \
        const int _col = _ct * 16 + m;                                          \
        const bf16x8 _b = *(const bf16x8*)(_Bb + _col * 128 +                   \
                              (_kb ^ ((unsigned)((_col & 7) << 4))));           \
        acc[0][_ct] = __builtin_amdgcn_mfma_f32_16x16x32_bf16(frag[0][_kt], _b, \
                                                              acc[0][_ct], 0, 0, 0);\
        acc[1][_ct] = __builtin_amdgcn_mfma_f32_16x16x32_bf16(frag[1][_kt], _b, \
                                                              acc[1][_ct], 0, 0, 0);\
      }                                                                         \
    }                                                                           \
  } while (0)

#define K4_BARRIER()                                                            \
  do {                                                                          \
    asm volatile("s_waitcnt vmcnt(2)" ::: "memory");                            \
    __builtin_amdgcn_sched_barrier(0);                                          \
    __builtin_amdgcn_s_barrier();                                               \
    __builtin_amdgcn_sched_barrier(0);                                          \
  } while (0)

#define K4_SUB(IT, BUF, BCUR, BNXT, ISLAST)                                     \
  do {                                                                          \
    if (!(ISLAST)) {                                                            \
      K4_STAGE((BUF) ^ 1, (IT) + 1);                                            \
      __builtin_amdgcn_sched_barrier(0);                                        \
    }                                                                           \
    K4_COMPUTE(BCUR, IT);                                                       \
    if (!(ISLAST)) K4_PREFETCH(BNXT, (IT) + 1);                                 \
    K4_MFMA(BUF);                                                               \
    if (!(ISLAST)) K4_BARRIER();                                                \
  } while (0)

__global__ __launch_bounds__(256, 2) void k4_attn(const unsigned char* __restrict__ bm,
                                                  const unsigned short* __restrict__ hT,
                                                  const float* __restrict__ s1,
                                                  const float* __restrict__ s2,
                                                  const float* __restrict__ s2max,
                                                  unsigned short* __restrict__ accp,
                                                  float* __restrict__ denp) {
  __shared__ __align__(16) char B_lds[2][256 * 128];
  __shared__ __align__(16) float s2_lds[KRANGE];
  const int t = threadIdx.x;
  const int wv = t >> 6, l = t & 63;
  const int m = l & 15, ko = l >> 4;
  const int ko8 = ko * 8;
  // bijective XCD swizzle: bids of XCD x -> wgid [x*192,(x+1)*192) = parts 2x,2x+1.
  const int wgid = (blockIdx.x % 8) * 192 + blockIdx.x / 8;
  const int part = wgid / 96, rb = wgid % 96;
  const int row0 = rb * 128 + wv * 32;  // this wave's first row
  const int kbase = part * KRANGE;
  const int kword0 = kbase >> 6;

  const float S2MAX = s2max[0];
  float s1v[2], ML2[2], dsum[2];
#pragma unroll
  for (int rt = 0; rt < 2; ++rt) {
    s1v[rt] = s1[row0 + rt * 16 + m];
    const float tup = s1v[rt] + S2MAX;
    const float M = fmaxf(tup, ALPHA * tup);  // lrelu upper bound for this row
    ML2[rt] = M * LOG2E;
    dsum[rt] = 0.f;
  }
  f32x4 acc[2][16];
#pragma unroll
  for (int rt = 0; rt < 2; ++rt)
#pragma unroll
    for (int ct = 0; ct < 16; ++ct) acc[rt][ct] = f32x4{0.f, 0.f, 0.f, 0.f};

  const unsigned char* bmr0 = bm + (size_t)(row0 + m) * (NN / 8) + (kbase >> 3);
  const unsigned char* bmr1 = bmr0 + (size_t)16 * (NN / 8);
  u32x2 bmE[2], bmO[2];
  bf16x8 frag[2][2];

  // prologue: s2 tile (3 KB) -> LDS, B tile 0 -> LDS, bitmap words 0 -> regs
  {
    if (wv < 3)
      GLDS16((const char*)(s2 + kbase) + (size_t)t * 16, (char*)s2_lds + ((size_t)wv << 10));
    K4_STAGE(0, 0);
    __builtin_amdgcn_sched_barrier(0);
    K4_PREFETCH(bmE, 0);
    K4_BARRIER();  // vmcnt(2): waits s2+B0, leaves the 2 bitmap loads in flight
  }

#pragma unroll 1
  for (int it = 0; it < NIT - 2; it += 2) {
    K4_SUB(it, 0, bmE, bmO, false);
    K4_SUB(it + 1, 1, bmO, bmE, false);
  }
  K4_SUB(NIT - 2, 0, bmE, bmO, false);
  K4_SUB(NIT - 1, 1, bmO, bmE, true);

  // denominator: sum the 4 k-octet lanes of each row
#pragma unroll
  for (int rt = 0; rt < 2; ++rt) {
    dsum[rt] += __shfl_xor(dsum[rt], 16);
    dsum[rt] += __shfl_xor(dsum[rt], 32);
  }
  if (l < 16) {
    denp[(size_t)part * NN + row0 + l] = dsum[0];
    denp[(size_t)part * NN + row0 + 16 + l] = dsum[1];
  }
  unsigned short* ap = accp + (size_t)part * NN * OUTF;
#pragma unroll
  for (int rt = 0; rt < 2; ++rt)
#pragma unroll
    for (int ct = 0; ct < 16; ++ct) {
      const int col = ct * 16 + m;
      const int grow = row0 + rt * 16 + ko * 4;
#pragma unroll
      for (int j = 0; j < 4; ++j)
        ap[(size_t)(grow + j) * OUTF + col] = f2bf(acc[rt][ct][j]);
    }
}

// ---------------- K5: combine 16 bf16 partials, divide, ELU --------------------------------
__global__ __launch_bounds__(256) void k5_combine(const unsigned short* __restrict__ accp,
                                                  const float* __restrict__ denp,
                                                  float* __restrict__ out) {
  const int idx = blockIdx.x * 256 + threadIdx.x;  // 4 floats per thread
  const int row = idx >> 6;
  f32x4 v = f32x4{0.f, 0.f, 0.f, 0.f};
  float den = 0.f;
#pragma unroll
  for (int p = 0; p < PARTS; ++p) {
    const u16x4 pv = *(const u16x4*)(accp + (size_t)p * NN * OUTF + (size_t)idx * 4);
    v.x += bf2f(pv.x); v.y += bf2f(pv.y); v.z += bf2f(pv.z); v.w += bf2f(pv.w);
    den += denp[(size_t)p * NN + row];
  }
  const float inv = 1.f / den;
  f32x4 r;
#pragma unroll
  for (int j = 0; j < 4; ++j) {
    const float x = v[j] * inv;
    r[j] = x > 0.f ? x : (__expf(x) - 1.f);
  }
  *(f32x4*)(out + (size_t)idx * 4) = r;
}

// ---------------- launch -------------------------------------------------------------------
extern "C" void kernel_launch(void* const* d_in, const int* in_sizes, int n_in,
                              void* d_out, int out_size, void* d_ws, size_t ws_size,
                              hipStream_t stream) {
  const float* inp = (const float*)d_in[0];
  const int*   adj = (const int*)d_in[1];
  const float* W   = (const float*)d_in[2];
  const float* a1  = (const float*)d_in[3];
  const float* a2  = (const float*)d_in[4];
  float* out = (float*)d_out;
  char* ws = (char*)d_ws;

  // ws layout (~121 MB)
  unsigned short* hT  = (unsigned short*)(ws + 0);            //   6,291,456 B
  float* s1   = (float*)(ws + 6291456);                       //      49,152 B
  float* s2   = (float*)(ws + 6340608);                       //      49,152 B
  float* s2m  = (float*)(ws + 6389760);                       //         256 B
  unsigned char* bmp = (unsigned char*)(ws + 6390016);        //  18,874,368 B
  unsigned short* accp = (unsigned short*)(ws + 25264384);    // 100,663,296 B (bf16 x 16)
  float* denp = (float*)(ws + 125927680);                     //     786,432 B

  kc_bitmap<<<dim3(2048), dim3(256), 0, stream>>>(adj, bmp);
  k1_gemm_h<<<dim3(NN / 32), dim3(256), 0, stream>>>(inp, W, a1, a2, hT, s1, s2);
  k3_s2max<<<dim3(1), dim3(1024), 0, stream>>>(s2, s2m);
  k4_attn<<<dim3(96 * PARTS), dim3(256), 0, stream>>>(bmp, hT, s1, s2, s2m, accp, denp);
  k5_combine<<<dim3(NN * OUTF / 1024), dim3(256), 0, stream>>>(accp, denp, out);
}